// Round 3
// baseline (11404.721 us; speedup 1.0000x reference)
//
#include <hip/hip_runtime.h>

#define DEV_INLINE __device__ __forceinline__

static const int SCAN_B = 512;

DEV_INLINE int lower_bound_i(const int* __restrict__ a, int n, int v) {
    int lo = 0, hi = n;
    while (lo < hi) { int m = (lo + hi) >> 1; if (a[m] < v) lo = m + 1; else hi = m; }
    return lo;
}

// h[e][0:16] += wrow[0:16] * x[e]  -- one LDS weight-row read feeds E*16 FMAs
template<int E>
DEV_INLINE void acc_row16(float (&h)[E][16], const float* wrow, const float (&x)[E]) {
    const float4* wr = (const float4*)wrow;
    float4 w0 = wr[0], w1 = wr[1], w2 = wr[2], w3 = wr[3];
#pragma unroll
    for (int e = 0; e < E; e++) {
        float xe = x[e];
        h[e][0]  += w0.x * xe; h[e][1]  += w0.y * xe; h[e][2]  += w0.z * xe; h[e][3]  += w0.w * xe;
        h[e][4]  += w1.x * xe; h[e][5]  += w1.y * xe; h[e][6]  += w1.z * xe; h[e][7]  += w1.w * xe;
        h[e][8]  += w2.x * xe; h[e][9]  += w2.y * xe; h[e][10] += w2.z * xe; h[e][11] += w2.w * xe;
        h[e][12] += w3.x * xe; h[e][13] += w3.y * xe; h[e][14] += w3.z * xe; h[e][15] += w3.w * xe;
    }
}

// Accumulate a 4*NQ-wide input segment (rows p[e], feature base c0) into h.
template<int E, int NQ>
DEV_INLINE void seg_acc(float (&h)[E][16], const float* wbase, int c0,
                        const float* (&p)[E]) {
#pragma unroll
    for (int q = 0; q < NQ; q++) {
        float4 a[E];
#pragma unroll
        for (int e = 0; e < E; e++) a[e] = ((const float4*)p[e])[q];
#pragma unroll
        for (int s = 0; s < 4; s++) {
            const float* wrow = wbase + (size_t)(c0 + q * 4 + s) * 16;
            float x[E];
#pragma unroll
            for (int e = 0; e < E; e++)
                x[e] = (s == 0) ? a[e].x : (s == 1) ? a[e].y : (s == 2) ? a[e].z : a[e].w;
            acc_row16<E>(h, wrow, x);
        }
    }
}

// ========================= CSR build (once per launch) ======================
__global__ void hist_kernel(const int* __restrict__ receivers, int n_edges,
                            int* __restrict__ cnt) {
    int i = blockIdx.x * blockDim.x + threadIdx.x;
    if (i < n_edges) atomicAdd(&cnt[receivers[i]], 1);
}

__global__ __launch_bounds__(SCAN_B)
void scan_block_kernel(const int* __restrict__ cnt, int n,
                       int* __restrict__ scan_tmp, int* __restrict__ blk_sum) {
    __shared__ int s[SCAN_B];
    int tid = threadIdx.x;
    int i = blockIdx.x * SCAN_B + tid;
    int v = (i < n) ? cnt[i] : 0;
    s[tid] = v;
    __syncthreads();
    for (int off = 1; off < SCAN_B; off <<= 1) {
        int t = (tid >= off) ? s[tid - off] : 0;
        __syncthreads();
        s[tid] += t;
        __syncthreads();
    }
    if (i < n) scan_tmp[i] = s[tid];
    if (tid == SCAN_B - 1) blk_sum[blockIdx.x] = s[tid];
}

__global__ __launch_bounds__(1024)
void scan_top_kernel(int* __restrict__ blk_sum, int nb, int* __restrict__ blk_off) {
    __shared__ int s[1024];
    int tid = threadIdx.x;
    int v = (tid < nb) ? blk_sum[tid] : 0;
    s[tid] = v;
    __syncthreads();
    for (int off = 1; off < 1024; off <<= 1) {
        int t = (tid >= off) ? s[tid - off] : 0;
        __syncthreads();
        s[tid] += t;
        __syncthreads();
    }
    if (tid < nb) blk_off[tid] = s[tid] - v;   // exclusive
}

__global__ __launch_bounds__(SCAN_B)
void scan_finalize_kernel(const int* __restrict__ cnt, const int* __restrict__ scan_tmp,
                          const int* __restrict__ blk_off, int n,
                          int* __restrict__ row_ptr, int* __restrict__ running) {
    int i = blockIdx.x * SCAN_B + threadIdx.x;
    if (i >= n) return;
    int incl = scan_tmp[i] + blk_off[i / SCAN_B];
    row_ptr[i + 1] = incl;
    running[i] = incl - cnt[i];
    if (i == 0) row_ptr[0] = 0;
}

__global__ void fill_kernel(const int* __restrict__ receivers, int n_edges,
                            int* __restrict__ running, int* __restrict__ col_idx) {
    int e = blockIdx.x * blockDim.x + threadIdx.x;
    if (e >= n_edges) return;
    int pos = atomicAdd(&running[receivers[e]], 1);
    col_idx[pos] = e;
}

// ---------------- Edge block: 112 -> 16 -> 16 -> 32, E=4 edges/thread -------
__global__ __launch_bounds__(256)
void edge_block_kernel(const float* __restrict__ edges_in,
                       const float* __restrict__ nodes_in,
                       const float* __restrict__ glob_in,
                       const int* __restrict__ senders,
                       const int* __restrict__ receivers,
                       const int* __restrict__ edge_gid,
                       const float* __restrict__ W1, const float* __restrict__ B1,
                       const float* __restrict__ W2, const float* __restrict__ B2,
                       const float* __restrict__ W3, const float* __restrict__ B3,
                       float* __restrict__ edges_out,
                       int n_edges) {
    __shared__ float w[2624];
    float* w1 = w;          // 112*16 = 1792
    float* b1 = w + 1792;   // 16
    float* w2 = w + 1808;   // 256
    float* b2 = w + 2064;   // 16
    float* w3 = w + 2080;   // 512
    float* b3 = w + 2592;   // 32
    for (int i = threadIdx.x; i < 1792; i += blockDim.x) w1[i] = W1[i];
    for (int i = threadIdx.x; i < 16;   i += blockDim.x) b1[i] = B1[i];
    for (int i = threadIdx.x; i < 256;  i += blockDim.x) w2[i] = W2[i];
    for (int i = threadIdx.x; i < 16;   i += blockDim.x) b2[i] = B2[i];
    for (int i = threadIdx.x; i < 512;  i += blockDim.x) w3[i] = W3[i];
    for (int i = threadIdx.x; i < 32;   i += blockDim.x) b3[i] = B3[i];
    __syncthreads();

    const int t = threadIdx.x;
    const int base = blockIdx.x * 1024;

    int  idx[4];
    bool val[4];
#pragma unroll
    for (int k = 0; k < 4; k++) {
        int e = base + t + k * 256;
        val[k] = (e < n_edges);
        idx[k] = val[k] ? e : 0;
    }

    int rr[4], ss[4], gg[4];
#pragma unroll
    for (int k = 0; k < 4; k++) { rr[k] = receivers[idx[k]]; ss[k] = senders[idx[k]]; gg[k] = edge_gid[idx[k]]; }

    float h1[4][16];
#pragma unroll
    for (int k = 0; k < 4; k++)
#pragma unroll
        for (int j = 0; j < 16; j++) h1[k][j] = b1[j];

    {   // 0..31: edge features
        const float* p[4];
#pragma unroll
        for (int k = 0; k < 4; k++) p[k] = edges_in + (size_t)idx[k] * 32;
        seg_acc<4, 8>(h1, w1, 0, p);
    }
    {   // 32..63: nodes[receiver]
        const float* p[4];
#pragma unroll
        for (int k = 0; k < 4; k++) p[k] = nodes_in + (size_t)rr[k] * 32;
        seg_acc<4, 8>(h1, w1, 32, p);
    }
    {   // 64..95: nodes[sender]
        const float* p[4];
#pragma unroll
        for (int k = 0; k < 4; k++) p[k] = nodes_in + (size_t)ss[k] * 32;
        seg_acc<4, 8>(h1, w1, 64, p);
    }
    {   // 96..111: globals[edge_gid]
        const float* p[4];
#pragma unroll
        for (int k = 0; k < 4; k++) p[k] = glob_in + (size_t)gg[k] * 16;
        seg_acc<4, 4>(h1, w1, 96, p);
    }

    float h2[4][16];
#pragma unroll
    for (int k = 0; k < 4; k++)
#pragma unroll
        for (int j = 0; j < 16; j++) h2[k][j] = b2[j];
#pragma unroll
    for (int r = 0; r < 16; r++) {
        float x[4];
#pragma unroll
        for (int k = 0; k < 4; k++) x[k] = fmaxf(h1[k][r], 0.0f);
        acc_row16<4>(h2, w2 + r * 16, x);
    }

    // Layer 3 in two 16-column halves (keeps accumulator at 64 VGPRs)
#pragma unroll
    for (int ph = 0; ph < 2; ph++) {
        float o[4][16];
#pragma unroll
        for (int k = 0; k < 4; k++)
#pragma unroll
            for (int j = 0; j < 16; j++) o[k][j] = b3[ph * 16 + j];
#pragma unroll
        for (int r = 0; r < 16; r++) {
            float x[4];
#pragma unroll
            for (int k = 0; k < 4; k++) x[k] = fmaxf(h2[k][r], 0.0f);
            acc_row16<4>(o, w3 + r * 32 + ph * 16, x);
        }
#pragma unroll
        for (int k = 0; k < 4; k++) {
            if (!val[k]) continue;
            float4* eo = (float4*)(edges_out + (size_t)idx[k] * 32 + ph * 16);
#pragma unroll
            for (int j4 = 0; j4 < 4; j4++)
                eo[j4] = make_float4(o[k][j4 * 4 + 0], o[k][j4 * 4 + 1],
                                     o[k][j4 * 4 + 2], o[k][j4 * 4 + 3]);
        }
    }
}

// -------- Receiver aggregation via CSR gather: 8 lanes per node -------------
__global__ __launch_bounds__(256)
void agg_mean_kernel(const float* __restrict__ edges_data,
                     const int* __restrict__ col_idx,
                     const int* __restrict__ row_ptr,
                     float* __restrict__ agg_mean, int n_nodes) {
    int node = blockIdx.x * 32 + (threadIdx.x >> 3);
    int lane = threadIdx.x & 7;
    if (node >= n_nodes) return;
    int lo = row_ptr[node], hi = row_ptr[node + 1];
    float4 acc = make_float4(0.f, 0.f, 0.f, 0.f);
    for (int e = lo; e < hi; e++) {
        int idx = col_idx[e];
        float4 v = ((const float4*)(edges_data + (size_t)idx * 32))[lane];
        acc.x += v.x; acc.y += v.y; acc.z += v.z; acc.w += v.w;
    }
    float inv = 1.0f / fmaxf((float)(hi - lo), 1.0f);
    ((float4*)(agg_mean + (size_t)node * 32))[lane] =
        make_float4(acc.x * inv, acc.y * inv, acc.z * inv, acc.w * inv);
}

// ---------------- Node block: 80 -> 16 -> 16 -> 32, E=2 nodes/thread --------
__global__ __launch_bounds__(256)
void node_block_kernel(const float* __restrict__ agg_mean,
                       const float* __restrict__ nodes_in,
                       const float* __restrict__ glob_in,
                       const int* __restrict__ node_gid,
                       const float* __restrict__ W1, const float* __restrict__ B1,
                       const float* __restrict__ W2, const float* __restrict__ B2,
                       const float* __restrict__ W3, const float* __restrict__ B3,
                       float* __restrict__ nodes_out,
                       int n_nodes) {
    __shared__ float w[2112];
    float* w1 = w;          // 80*16 = 1280
    float* b1 = w + 1280;   // 16
    float* w2 = w + 1296;   // 256
    float* b2 = w + 1552;   // 16
    float* w3 = w + 1568;   // 512
    float* b3 = w + 2080;   // 32
    for (int i = threadIdx.x; i < 1280; i += blockDim.x) w1[i] = W1[i];
    for (int i = threadIdx.x; i < 16;   i += blockDim.x) b1[i] = B1[i];
    for (int i = threadIdx.x; i < 256;  i += blockDim.x) w2[i] = W2[i];
    for (int i = threadIdx.x; i < 16;   i += blockDim.x) b2[i] = B2[i];
    for (int i = threadIdx.x; i < 512;  i += blockDim.x) w3[i] = W3[i];
    for (int i = threadIdx.x; i < 32;   i += blockDim.x) b3[i] = B3[i];
    __syncthreads();

    const int t = threadIdx.x;
    const int base = blockIdx.x * 512;

    int  idx[2];
    bool val[2];
#pragma unroll
    for (int k = 0; k < 2; k++) {
        int n = base + t + k * 256;
        val[k] = (n < n_nodes);
        idx[k] = val[k] ? n : 0;
    }
    int gg[2];
#pragma unroll
    for (int k = 0; k < 2; k++) gg[k] = node_gid[idx[k]];

    float h1[2][16];
#pragma unroll
    for (int k = 0; k < 2; k++)
#pragma unroll
        for (int j = 0; j < 16; j++) h1[k][j] = b1[j];

    {   // 0..31: mean of received edges (pre-averaged)
        const float* p[2];
#pragma unroll
        for (int k = 0; k < 2; k++) p[k] = agg_mean + (size_t)idx[k] * 32;
        seg_acc<2, 8>(h1, w1, 0, p);
    }
    {   // 32..63: nodes
        const float* p[2];
#pragma unroll
        for (int k = 0; k < 2; k++) p[k] = nodes_in + (size_t)idx[k] * 32;
        seg_acc<2, 8>(h1, w1, 32, p);
    }
    {   // 64..79: globals[node_gid]
        const float* p[2];
#pragma unroll
        for (int k = 0; k < 2; k++) p[k] = glob_in + (size_t)gg[k] * 16;
        seg_acc<2, 4>(h1, w1, 64, p);
    }

    float h2[2][16];
#pragma unroll
    for (int k = 0; k < 2; k++)
#pragma unroll
        for (int j = 0; j < 16; j++) h2[k][j] = b2[j];
#pragma unroll
    for (int r = 0; r < 16; r++) {
        float x[2];
#pragma unroll
        for (int k = 0; k < 2; k++) x[k] = fmaxf(h1[k][r], 0.0f);
        acc_row16<2>(h2, w2 + r * 16, x);
    }

#pragma unroll
    for (int ph = 0; ph < 2; ph++) {
        float o[2][16];
#pragma unroll
        for (int k = 0; k < 2; k++)
#pragma unroll
            for (int j = 0; j < 16; j++) o[k][j] = b3[ph * 16 + j];
#pragma unroll
        for (int r = 0; r < 16; r++) {
            float x[2];
#pragma unroll
            for (int k = 0; k < 2; k++) x[k] = fmaxf(h2[k][r], 0.0f);
            acc_row16<2>(o, w3 + r * 32 + ph * 16, x);
        }
#pragma unroll
        for (int k = 0; k < 2; k++) {
            if (!val[k]) continue;
            float4* no = (float4*)(nodes_out + (size_t)idx[k] * 32 + ph * 16);
#pragma unroll
            for (int j4 = 0; j4 < 4; j4++)
                no[j4] = make_float4(o[k][j4 * 4 + 0], o[k][j4 * 4 + 1],
                                     o[k][j4 * 4 + 2], o[k][j4 * 4 + 3]);
        }
    }
}

// ---------------- Per-graph sums over sorted gid ranges ---------------------
__global__ __launch_bounds__(256)
void graph_sum_kernel(const float* __restrict__ x, const int* __restrict__ gid,
                      int n_rows, float* __restrict__ sums, int splits) {
    int g = blockIdx.x / splits;
    int s = blockIdx.x % splits;
    int lo = lower_bound_i(gid, n_rows, g);
    int hi = lower_bound_i(gid, n_rows, g + 1);
    int len = hi - lo;
    int chunk = (len + splits - 1) / splits;
    int rlo = lo + s * chunk;
    int rhi = min(rlo + chunk, hi);

    int c = threadIdx.x & 31;
    int rg = threadIdx.x >> 5;   // 8 row-groups with 256 threads
    float acc = 0.0f;
    for (int r = rlo + rg; r < rhi; r += 8)
        acc += x[(size_t)r * 32 + c];

    __shared__ float red[256];
    red[threadIdx.x] = acc;
    __syncthreads();
    if (threadIdx.x < 32) {
        float ssum = 0.0f;
#pragma unroll
        for (int i = 0; i < 8; i++) ssum += red[i * 32 + threadIdx.x];
        atomicAdd(&sums[g * 32 + threadIdx.x], ssum);
    }
}

// ---------------- Global block: 80 -> 16 -> 16 -> 16 ------------------------
__global__ __launch_bounds__(64)
void global_block_kernel(const float* __restrict__ gsum_e,
                         const float* __restrict__ gsum_n,
                         const float* __restrict__ glob_in,
                         const int* __restrict__ edge_gid, int n_edges,
                         const int* __restrict__ node_gid, int n_nodes,
                         const float* __restrict__ W1, const float* __restrict__ B1,
                         const float* __restrict__ W2, const float* __restrict__ B2,
                         const float* __restrict__ W3, const float* __restrict__ B3,
                         float* __restrict__ glob_out, int n_graph) {
    __shared__ float w[1840];
    float* w1 = w;          // 80*16 = 1280
    float* b1 = w + 1280;   // 16
    float* w2 = w + 1296;   // 256
    float* b2 = w + 1552;   // 16
    float* w3 = w + 1568;   // 16*16 = 256
    float* b3 = w + 1824;   // 16
    for (int i = threadIdx.x; i < 1280; i += blockDim.x) w1[i] = W1[i];
    for (int i = threadIdx.x; i < 16;   i += blockDim.x) b1[i] = B1[i];
    for (int i = threadIdx.x; i < 256;  i += blockDim.x) w2[i] = W2[i];
    for (int i = threadIdx.x; i < 16;   i += blockDim.x) b2[i] = B2[i];
    for (int i = threadIdx.x; i < 256;  i += blockDim.x) w3[i] = W3[i];
    for (int i = threadIdx.x; i < 16;   i += blockDim.x) b3[i] = B3[i];
    __syncthreads();

    int g = threadIdx.x;
    if (g >= n_graph) return;

    int ecnt = lower_bound_i(edge_gid, n_edges, g + 1) - lower_bound_i(edge_gid, n_edges, g);
    int ncnt = lower_bound_i(node_gid, n_nodes, g + 1) - lower_bound_i(node_gid, n_nodes, g);
    float inv_e = 1.0f / fmaxf((float)ecnt, 1.0f);
    float inv_n = 1.0f / fmaxf((float)ncnt, 1.0f);

    float in[80];
#pragma unroll
    for (int c = 0; c < 32; c++) in[c] = gsum_e[g * 32 + c] * inv_e;
#pragma unroll
    for (int c = 0; c < 32; c++) in[32 + c] = gsum_n[g * 32 + c] * inv_n;
#pragma unroll
    for (int c = 0; c < 16; c++) in[64 + c] = glob_in[g * 16 + c];

    float h1[16];
#pragma unroll
    for (int j = 0; j < 16; j++) h1[j] = b1[j];
#pragma unroll
    for (int k = 0; k < 80; k++) {
        float x = in[k];
#pragma unroll
        for (int j = 0; j < 16; j++) h1[j] += w1[k * 16 + j] * x;
    }
    float h2[16];
#pragma unroll
    for (int j = 0; j < 16; j++) h2[j] = b2[j];
#pragma unroll
    for (int k = 0; k < 16; k++) {
        float x = fmaxf(h1[k], 0.0f);
#pragma unroll
        for (int j = 0; j < 16; j++) h2[j] += w2[k * 16 + j] * x;
    }
    float o[16];
#pragma unroll
    for (int j = 0; j < 16; j++) o[j] = b3[j];
#pragma unroll
    for (int k = 0; k < 16; k++) {
        float x = fmaxf(h2[k], 0.0f);
#pragma unroll
        for (int j = 0; j < 16; j++) o[j] += w3[k * 16 + j] * x;
    }
#pragma unroll
    for (int j = 0; j < 16; j++) glob_out[g * 16 + j] = o[j];
}

extern "C" void kernel_launch(void* const* d_in, const int* in_sizes, int n_in,
                              void* d_out, int out_size, void* d_ws, size_t ws_size,
                              hipStream_t stream) {
    const float* d_nodes = (const float*)d_in[0];
    const float* d_edges = (const float*)d_in[1];
    const float* d_glob  = (const float*)d_in[2];
    const int* senders   = (const int*)d_in[3];
    const int* receivers = (const int*)d_in[4];
    const int* node_gid  = (const int*)d_in[5];
    const int* edge_gid  = (const int*)d_in[6];
    const float* e_w1 = (const float*)d_in[7];
    const float* e_b1 = (const float*)d_in[8];
    const float* e_w2 = (const float*)d_in[9];
    const float* e_b2 = (const float*)d_in[10];
    const float* e_w3 = (const float*)d_in[11];
    const float* e_b3 = (const float*)d_in[12];
    const float* n_w1 = (const float*)d_in[13];
    const float* n_b1 = (const float*)d_in[14];
    const float* n_w2 = (const float*)d_in[15];
    const float* n_b2 = (const float*)d_in[16];
    const float* n_w3 = (const float*)d_in[17];
    const float* n_b3 = (const float*)d_in[18];
    const float* g_w1 = (const float*)d_in[19];
    const float* g_b1 = (const float*)d_in[20];
    const float* g_w2 = (const float*)d_in[21];
    const float* g_b2 = (const float*)d_in[22];
    const float* g_w3 = (const float*)d_in[23];
    const float* g_b3 = (const float*)d_in[24];

    const int n_nodes = in_sizes[0] / 32;
    const int n_edges = in_sizes[1] / 32;
    const int n_graph = in_sizes[2] / 16;

    float* out_nodes = (float*)d_out;                        // n_nodes*32
    float* out_edges = out_nodes + (size_t)n_nodes * 32;     // n_edges*32
    float* out_glob  = out_edges + (size_t)n_edges * 32;     // n_graph*16

    float* ws = (float*)d_ws;
    float* ws_edges = ws;  ws += (size_t)n_edges * 32;
    float* ws_nodes = ws;  ws += (size_t)n_nodes * 32;
    float* agg_mean = ws;  ws += (size_t)n_nodes * 32;
    float* gA       = ws;  ws += (size_t)n_graph * 16;
    float* gB       = ws;  ws += (size_t)n_graph * 16;
    float* gsum_e   = ws;  ws += (size_t)n_graph * 32;
    float* gsum_n   = ws;  ws += (size_t)n_graph * 32;

    int* wi = (int*)ws;
    int* cnt      = wi;  wi += n_nodes;
    int* row_ptr  = wi;  wi += n_nodes + 1;
    int* running  = wi;  wi += n_nodes;
    int* scan_tmp = wi;  wi += n_nodes;
    int* col_idx  = wi;  wi += n_edges;
    int* blk_sum  = wi;  wi += 1024;
    int* blk_off  = wi;  wi += 1024;

    const int nblocks_scan = (n_nodes + SCAN_B - 1) / SCAN_B;

    // ---- CSR build (receivers constant across passes) ----
    hipMemsetAsync(cnt, 0, (size_t)n_nodes * sizeof(int), stream);
    hist_kernel<<<(n_edges + 255) / 256, 256, 0, stream>>>(receivers, n_edges, cnt);
    scan_block_kernel<<<nblocks_scan, SCAN_B, 0, stream>>>(cnt, n_nodes, scan_tmp, blk_sum);
    scan_top_kernel<<<1, 1024, 0, stream>>>(blk_sum, nblocks_scan, blk_off);
    scan_finalize_kernel<<<nblocks_scan, SCAN_B, 0, stream>>>(cnt, scan_tmp, blk_off,
                                                              n_nodes, row_ptr, running);
    fill_kernel<<<(n_edges + 255) / 256, 256, 0, stream>>>(receivers, n_edges, running, col_idx);

    const float* nodes_in = d_nodes;
    const float* edges_in = d_edges;
    const float* glob_in  = d_glob;

    for (int pass = 0; pass < 3; ++pass) {
        float* nodes_out; float* edges_out; float* glob_out;
        if (pass == 0)      { nodes_out = out_nodes; edges_out = out_edges; glob_out = gA; }
        else if (pass == 1) { nodes_out = ws_nodes;  edges_out = ws_edges;  glob_out = gB; }
        else                { nodes_out = out_nodes; edges_out = out_edges; glob_out = out_glob; }

        hipMemsetAsync(gsum_e, 0, (size_t)n_graph * 32 * sizeof(float), stream);
        hipMemsetAsync(gsum_n, 0, (size_t)n_graph * 32 * sizeof(float), stream);

        edge_block_kernel<<<(n_edges + 1023) / 1024, 256, 0, stream>>>(
            edges_in, nodes_in, glob_in, senders, receivers, edge_gid,
            e_w1, e_b1, e_w2, e_b2, e_w3, e_b3,
            edges_out, n_edges);

        graph_sum_kernel<<<n_graph * 16, 256, 0, stream>>>(edges_out, edge_gid, n_edges, gsum_e, 16);

        agg_mean_kernel<<<(n_nodes + 31) / 32, 256, 0, stream>>>(
            edges_out, col_idx, row_ptr, agg_mean, n_nodes);

        node_block_kernel<<<(n_nodes + 511) / 512, 256, 0, stream>>>(
            agg_mean, nodes_in, glob_in, node_gid,
            n_w1, n_b1, n_w2, n_b2, n_w3, n_b3,
            nodes_out, n_nodes);

        graph_sum_kernel<<<n_graph * 4, 256, 0, stream>>>(nodes_out, node_gid, n_nodes, gsum_n, 4);

        global_block_kernel<<<1, 64, 0, stream>>>(
            gsum_e, gsum_n, glob_in, edge_gid, n_edges, node_gid, n_nodes,
            g_w1, g_b1, g_w2, g_b2, g_w3, g_b3,
            glob_out, n_graph);

        nodes_in = nodes_out;
        edges_in = edges_out;
        glob_in  = glob_out;
    }
}

// Round 4
// 912.367 us; speedup vs baseline: 12.5001x; 12.5001x over previous
//
#include <hip/hip_runtime.h>

#define DEV_INLINE __device__ __forceinline__

static const int SCAN_B = 512;

DEV_INLINE int lower_bound_i(const int* __restrict__ a, int n, int v) {
    int lo = 0, hi = n;
    while (lo < hi) { int m = (lo + hi) >> 1; if (a[m] < v) lo = m + 1; else hi = m; }
    return lo;
}

// Load NF contiguous floats into registers via float4.
template<int NF>
DEV_INLINE void load_row(const float* __restrict__ p, float (&x)[NF]) {
#pragma unroll
    for (int q = 0; q < NF / 4; q++) {
        float4 v = ((const float4*)p)[q];
        x[q * 4 + 0] = v.x; x[q * 4 + 1] = v.y; x[q * 4 + 2] = v.z; x[q * 4 + 3] = v.w;
    }
}

// h[0:16] += sum_k x[k] * W[k*16 + j]   (W uniform address -> s_load;
// v_fmac_f32 with one SGPR operand runs at full VALU rate)
template<int K>
DEV_INLINE void dense16(float (&h)[16], const float* __restrict__ W, const float (&x)[K]) {
#pragma unroll
    for (int k = 0; k < K; k++)
#pragma unroll
        for (int j = 0; j < 16; j++)
            h[j] = fmaf(x[k], W[k * 16 + j], h[j]);
}

// ========================= CSR build (once per launch) ======================
__global__ void hist_kernel(const int* __restrict__ receivers, int n_edges,
                            int* __restrict__ cnt) {
    int i = blockIdx.x * blockDim.x + threadIdx.x;
    if (i < n_edges) atomicAdd(&cnt[receivers[i]], 1);
}

__global__ __launch_bounds__(SCAN_B)
void scan_block_kernel(const int* __restrict__ cnt, int n,
                       int* __restrict__ scan_tmp, int* __restrict__ blk_sum) {
    __shared__ int s[SCAN_B];
    int tid = threadIdx.x;
    int i = blockIdx.x * SCAN_B + tid;
    int v = (i < n) ? cnt[i] : 0;
    s[tid] = v;
    __syncthreads();
    for (int off = 1; off < SCAN_B; off <<= 1) {
        int t = (tid >= off) ? s[tid - off] : 0;
        __syncthreads();
        s[tid] += t;
        __syncthreads();
    }
    if (i < n) scan_tmp[i] = s[tid];
    if (tid == SCAN_B - 1) blk_sum[blockIdx.x] = s[tid];
}

__global__ __launch_bounds__(1024)
void scan_top_kernel(int* __restrict__ blk_sum, int nb, int* __restrict__ blk_off) {
    __shared__ int s[1024];
    int tid = threadIdx.x;
    int v = (tid < nb) ? blk_sum[tid] : 0;
    s[tid] = v;
    __syncthreads();
    for (int off = 1; off < 1024; off <<= 1) {
        int t = (tid >= off) ? s[tid - off] : 0;
        __syncthreads();
        s[tid] += t;
        __syncthreads();
    }
    if (tid < nb) blk_off[tid] = s[tid] - v;   // exclusive
}

__global__ __launch_bounds__(SCAN_B)
void scan_finalize_kernel(const int* __restrict__ cnt, const int* __restrict__ scan_tmp,
                          const int* __restrict__ blk_off, int n,
                          int* __restrict__ row_ptr, int* __restrict__ running) {
    int i = blockIdx.x * SCAN_B + threadIdx.x;
    if (i >= n) return;
    int incl = scan_tmp[i] + blk_off[i / SCAN_B];
    row_ptr[i + 1] = incl;
    running[i] = incl - cnt[i];
    if (i == 0) row_ptr[0] = 0;
}

__global__ void fill_kernel(const int* __restrict__ receivers, int n_edges,
                            int* __restrict__ running, int* __restrict__ col_idx) {
    int e = blockIdx.x * blockDim.x + threadIdx.x;
    if (e >= n_edges) return;
    int pos = atomicAdd(&running[receivers[e]], 1);
    col_idx[pos] = e;
}

// ---------------- Edge block: 112 -> 16 -> 16 -> 32 -------------------------
// Weights read directly from global with wave-uniform addresses (SGPR path).
// No LDS, no divergent early-return (clamped index, masked store).
__global__ __launch_bounds__(256)
void edge_block_kernel(const float* __restrict__ edges_in,
                       const float* __restrict__ nodes_in,
                       const float* __restrict__ glob_in,
                       const int* __restrict__ senders,
                       const int* __restrict__ receivers,
                       const int* __restrict__ edge_gid,
                       const float* __restrict__ W1, const float* __restrict__ B1,
                       const float* __restrict__ W2, const float* __restrict__ B2,
                       const float* __restrict__ W3, const float* __restrict__ B3,
                       float* __restrict__ edges_out,
                       int n_edges) {
    const int e0 = blockIdx.x * 256 + threadIdx.x;
    const int e  = min(e0, n_edges - 1);

    const int rr = receivers[e], ss = senders[e], gg = edge_gid[e];

    float h1[16];
#pragma unroll
    for (int j = 0; j < 16; j++) h1[j] = B1[j];

    {
        float x[32];
        load_row<32>(edges_in + (size_t)e * 32, x);
        dense16<32>(h1, W1 + 0 * 16, x);
        load_row<32>(nodes_in + (size_t)rr * 32, x);
        dense16<32>(h1, W1 + 32 * 16, x);
        load_row<32>(nodes_in + (size_t)ss * 32, x);
        dense16<32>(h1, W1 + 64 * 16, x);
    }
    {
        float xg[16];
        load_row<16>(glob_in + (size_t)gg * 16, xg);
        dense16<16>(h1, W1 + 96 * 16, xg);
    }

    float x2[16];
#pragma unroll
    for (int j = 0; j < 16; j++) x2[j] = fmaxf(h1[j], 0.0f);
    float h2[16];
#pragma unroll
    for (int j = 0; j < 16; j++) h2[j] = B2[j];
    dense16<16>(h2, W2, x2);

    float x3[16];
#pragma unroll
    for (int j = 0; j < 16; j++) x3[j] = fmaxf(h2[j], 0.0f);
    float o[32];
#pragma unroll
    for (int j = 0; j < 32; j++) o[j] = B3[j];
#pragma unroll
    for (int k = 0; k < 16; k++)
#pragma unroll
        for (int j = 0; j < 32; j++)
            o[j] = fmaf(x3[k], W3[k * 32 + j], o[j]);

    if (e0 < n_edges) {
        float4* eo = (float4*)(edges_out + (size_t)e0 * 32);
#pragma unroll
        for (int j4 = 0; j4 < 8; j4++)
            eo[j4] = make_float4(o[j4 * 4 + 0], o[j4 * 4 + 1], o[j4 * 4 + 2], o[j4 * 4 + 3]);
    }
}

// -------- Receiver aggregation via CSR gather: 8 lanes per node -------------
__global__ __launch_bounds__(256)
void agg_mean_kernel(const float* __restrict__ edges_data,
                     const int* __restrict__ col_idx,
                     const int* __restrict__ row_ptr,
                     float* __restrict__ agg_mean, int n_nodes) {
    int node = blockIdx.x * 32 + (threadIdx.x >> 3);
    int lane = threadIdx.x & 7;
    if (node >= n_nodes) return;
    int lo = row_ptr[node], hi = row_ptr[node + 1];
    float4 acc = make_float4(0.f, 0.f, 0.f, 0.f);
    for (int e = lo; e < hi; e++) {
        int idx = col_idx[e];
        float4 v = ((const float4*)(edges_data + (size_t)idx * 32))[lane];
        acc.x += v.x; acc.y += v.y; acc.z += v.z; acc.w += v.w;
    }
    float inv = 1.0f / fmaxf((float)(hi - lo), 1.0f);
    ((float4*)(agg_mean + (size_t)node * 32))[lane] =
        make_float4(acc.x * inv, acc.y * inv, acc.z * inv, acc.w * inv);
}

// ---------------- Node block: 80 -> 16 -> 16 -> 32 --------------------------
__global__ __launch_bounds__(256)
void node_block_kernel(const float* __restrict__ agg_mean,
                       const float* __restrict__ nodes_in,
                       const float* __restrict__ glob_in,
                       const int* __restrict__ node_gid,
                       const float* __restrict__ W1, const float* __restrict__ B1,
                       const float* __restrict__ W2, const float* __restrict__ B2,
                       const float* __restrict__ W3, const float* __restrict__ B3,
                       float* __restrict__ nodes_out,
                       int n_nodes) {
    const int n0 = blockIdx.x * 256 + threadIdx.x;
    const int n  = min(n0, n_nodes - 1);
    const int gg = node_gid[n];

    float h1[16];
#pragma unroll
    for (int j = 0; j < 16; j++) h1[j] = B1[j];

    {
        float x[32];
        load_row<32>(agg_mean + (size_t)n * 32, x);
        dense16<32>(h1, W1 + 0 * 16, x);
        load_row<32>(nodes_in + (size_t)n * 32, x);
        dense16<32>(h1, W1 + 32 * 16, x);
    }
    {
        float xg[16];
        load_row<16>(glob_in + (size_t)gg * 16, xg);
        dense16<16>(h1, W1 + 64 * 16, xg);
    }

    float x2[16];
#pragma unroll
    for (int j = 0; j < 16; j++) x2[j] = fmaxf(h1[j], 0.0f);
    float h2[16];
#pragma unroll
    for (int j = 0; j < 16; j++) h2[j] = B2[j];
    dense16<16>(h2, W2, x2);

    float x3[16];
#pragma unroll
    for (int j = 0; j < 16; j++) x3[j] = fmaxf(h2[j], 0.0f);
    float o[32];
#pragma unroll
    for (int j = 0; j < 32; j++) o[j] = B3[j];
#pragma unroll
    for (int k = 0; k < 16; k++)
#pragma unroll
        for (int j = 0; j < 32; j++)
            o[j] = fmaf(x3[k], W3[k * 32 + j], o[j]);

    if (n0 < n_nodes) {
        float4* no = (float4*)(nodes_out + (size_t)n0 * 32);
#pragma unroll
        for (int j4 = 0; j4 < 8; j4++)
            no[j4] = make_float4(o[j4 * 4 + 0], o[j4 * 4 + 1], o[j4 * 4 + 2], o[j4 * 4 + 3]);
    }
}

// ---------------- Per-graph sums over sorted gid ranges ---------------------
__global__ __launch_bounds__(256)
void graph_sum_kernel(const float* __restrict__ x, const int* __restrict__ gid,
                      int n_rows, float* __restrict__ sums, int splits) {
    int g = blockIdx.x / splits;
    int s = blockIdx.x % splits;
    int lo = lower_bound_i(gid, n_rows, g);
    int hi = lower_bound_i(gid, n_rows, g + 1);
    int len = hi - lo;
    int chunk = (len + splits - 1) / splits;
    int rlo = lo + s * chunk;
    int rhi = min(rlo + chunk, hi);

    int c = threadIdx.x & 31;
    int rg = threadIdx.x >> 5;   // 8 row-groups with 256 threads
    float acc = 0.0f;
    for (int r = rlo + rg; r < rhi; r += 8)
        acc += x[(size_t)r * 32 + c];

    __shared__ float red[256];
    red[threadIdx.x] = acc;
    __syncthreads();
    if (threadIdx.x < 32) {
        float ssum = 0.0f;
#pragma unroll
        for (int i = 0; i < 8; i++) ssum += red[i * 32 + threadIdx.x];
        atomicAdd(&sums[g * 32 + threadIdx.x], ssum);
    }
}

// ---------------- Global block: 80 -> 16 -> 16 -> 16 ------------------------
__global__ __launch_bounds__(64)
void global_block_kernel(const float* __restrict__ gsum_e,
                         const float* __restrict__ gsum_n,
                         const float* __restrict__ glob_in,
                         const int* __restrict__ edge_gid, int n_edges,
                         const int* __restrict__ node_gid, int n_nodes,
                         const float* __restrict__ W1, const float* __restrict__ B1,
                         const float* __restrict__ W2, const float* __restrict__ B2,
                         const float* __restrict__ W3, const float* __restrict__ B3,
                         float* __restrict__ glob_out, int n_graph) {
    const int g0 = threadIdx.x;
    const int g  = min(g0, n_graph - 1);

    int ecnt = lower_bound_i(edge_gid, n_edges, g + 1) - lower_bound_i(edge_gid, n_edges, g);
    int ncnt = lower_bound_i(node_gid, n_nodes, g + 1) - lower_bound_i(node_gid, n_nodes, g);
    float inv_e = 1.0f / fmaxf((float)ecnt, 1.0f);
    float inv_n = 1.0f / fmaxf((float)ncnt, 1.0f);

    float h1[16];
#pragma unroll
    for (int j = 0; j < 16; j++) h1[j] = B1[j];

    {
        float x[32];
        load_row<32>(gsum_e + (size_t)g * 32, x);
#pragma unroll
        for (int k = 0; k < 32; k++) x[k] *= inv_e;
        dense16<32>(h1, W1 + 0 * 16, x);
        load_row<32>(gsum_n + (size_t)g * 32, x);
#pragma unroll
        for (int k = 0; k < 32; k++) x[k] *= inv_n;
        dense16<32>(h1, W1 + 32 * 16, x);
    }
    {
        float xg[16];
        load_row<16>(glob_in + (size_t)g * 16, xg);
        dense16<16>(h1, W1 + 64 * 16, xg);
    }

    float x2[16];
#pragma unroll
    for (int j = 0; j < 16; j++) x2[j] = fmaxf(h1[j], 0.0f);
    float h2[16];
#pragma unroll
    for (int j = 0; j < 16; j++) h2[j] = B2[j];
    dense16<16>(h2, W2, x2);

    float x3[16];
#pragma unroll
    for (int j = 0; j < 16; j++) x3[j] = fmaxf(h2[j], 0.0f);
    float o[16];
#pragma unroll
    for (int j = 0; j < 16; j++) o[j] = B3[j];
    dense16<16>(o, W3, x3);

    if (g0 < n_graph) {
#pragma unroll
        for (int j = 0; j < 16; j++) glob_out[g0 * 16 + j] = o[j];
    }
}

extern "C" void kernel_launch(void* const* d_in, const int* in_sizes, int n_in,
                              void* d_out, int out_size, void* d_ws, size_t ws_size,
                              hipStream_t stream) {
    const float* d_nodes = (const float*)d_in[0];
    const float* d_edges = (const float*)d_in[1];
    const float* d_glob  = (const float*)d_in[2];
    const int* senders   = (const int*)d_in[3];
    const int* receivers = (const int*)d_in[4];
    const int* node_gid  = (const int*)d_in[5];
    const int* edge_gid  = (const int*)d_in[6];
    const float* e_w1 = (const float*)d_in[7];
    const float* e_b1 = (const float*)d_in[8];
    const float* e_w2 = (const float*)d_in[9];
    const float* e_b2 = (const float*)d_in[10];
    const float* e_w3 = (const float*)d_in[11];
    const float* e_b3 = (const float*)d_in[12];
    const float* n_w1 = (const float*)d_in[13];
    const float* n_b1 = (const float*)d_in[14];
    const float* n_w2 = (const float*)d_in[15];
    const float* n_b2 = (const float*)d_in[16];
    const float* n_w3 = (const float*)d_in[17];
    const float* n_b3 = (const float*)d_in[18];
    const float* g_w1 = (const float*)d_in[19];
    const float* g_b1 = (const float*)d_in[20];
    const float* g_w2 = (const float*)d_in[21];
    const float* g_b2 = (const float*)d_in[22];
    const float* g_w3 = (const float*)d_in[23];
    const float* g_b3 = (const float*)d_in[24];

    const int n_nodes = in_sizes[0] / 32;
    const int n_edges = in_sizes[1] / 32;
    const int n_graph = in_sizes[2] / 16;

    float* out_nodes = (float*)d_out;                        // n_nodes*32
    float* out_edges = out_nodes + (size_t)n_nodes * 32;     // n_edges*32
    float* out_glob  = out_edges + (size_t)n_edges * 32;     // n_graph*16

    float* ws = (float*)d_ws;
    float* ws_edges = ws;  ws += (size_t)n_edges * 32;
    float* ws_nodes = ws;  ws += (size_t)n_nodes * 32;
    float* agg_mean = ws;  ws += (size_t)n_nodes * 32;
    float* gA       = ws;  ws += (size_t)n_graph * 16;
    float* gB       = ws;  ws += (size_t)n_graph * 16;
    float* gsum_e   = ws;  ws += (size_t)n_graph * 32;
    float* gsum_n   = ws;  ws += (size_t)n_graph * 32;

    int* wi = (int*)ws;
    int* cnt      = wi;  wi += n_nodes;
    int* row_ptr  = wi;  wi += n_nodes + 1;
    int* running  = wi;  wi += n_nodes;
    int* scan_tmp = wi;  wi += n_nodes;
    int* col_idx  = wi;  wi += n_edges;
    int* blk_sum  = wi;  wi += 1024;
    int* blk_off  = wi;  wi += 1024;

    const int nblocks_scan = (n_nodes + SCAN_B - 1) / SCAN_B;

    // ---- CSR build (receivers constant across passes) ----
    hipMemsetAsync(cnt, 0, (size_t)n_nodes * sizeof(int), stream);
    hist_kernel<<<(n_edges + 255) / 256, 256, 0, stream>>>(receivers, n_edges, cnt);
    scan_block_kernel<<<nblocks_scan, SCAN_B, 0, stream>>>(cnt, n_nodes, scan_tmp, blk_sum);
    scan_top_kernel<<<1, 1024, 0, stream>>>(blk_sum, nblocks_scan, blk_off);
    scan_finalize_kernel<<<nblocks_scan, SCAN_B, 0, stream>>>(cnt, scan_tmp, blk_off,
                                                              n_nodes, row_ptr, running);
    fill_kernel<<<(n_edges + 255) / 256, 256, 0, stream>>>(receivers, n_edges, running, col_idx);

    const float* nodes_in = d_nodes;
    const float* edges_in = d_edges;
    const float* glob_in  = d_glob;

    for (int pass = 0; pass < 3; ++pass) {
        float* nodes_out; float* edges_out; float* glob_out;
        if (pass == 0)      { nodes_out = out_nodes; edges_out = out_edges; glob_out = gA; }
        else if (pass == 1) { nodes_out = ws_nodes;  edges_out = ws_edges;  glob_out = gB; }
        else                { nodes_out = out_nodes; edges_out = out_edges; glob_out = out_glob; }

        hipMemsetAsync(gsum_e, 0, (size_t)n_graph * 32 * sizeof(float), stream);
        hipMemsetAsync(gsum_n, 0, (size_t)n_graph * 32 * sizeof(float), stream);

        edge_block_kernel<<<(n_edges + 255) / 256, 256, 0, stream>>>(
            edges_in, nodes_in, glob_in, senders, receivers, edge_gid,
            e_w1, e_b1, e_w2, e_b2, e_w3, e_b3,
            edges_out, n_edges);

        graph_sum_kernel<<<n_graph * 16, 256, 0, stream>>>(edges_out, edge_gid, n_edges, gsum_e, 16);

        agg_mean_kernel<<<(n_nodes + 31) / 32, 256, 0, stream>>>(
            edges_out, col_idx, row_ptr, agg_mean, n_nodes);

        node_block_kernel<<<(n_nodes + 255) / 256, 256, 0, stream>>>(
            agg_mean, nodes_in, glob_in, node_gid,
            n_w1, n_b1, n_w2, n_b2, n_w3, n_b3,
            nodes_out, n_nodes);

        graph_sum_kernel<<<n_graph * 4, 256, 0, stream>>>(nodes_out, node_gid, n_nodes, gsum_n, 4);

        global_block_kernel<<<1, 64, 0, stream>>>(
            gsum_e, gsum_n, glob_in, edge_gid, n_edges, node_gid, n_nodes,
            g_w1, g_b1, g_w2, g_b2, g_w3, g_b3,
            glob_out, n_graph);

        nodes_in = nodes_out;
        edges_in = edges_out;
        glob_in  = glob_out;
    }
}